// Round 12
// baseline (1241.922 us; speedup 1.0000x reference)
//
#include <hip/hip_runtime.h>
#include <hip/hip_bf16.h>
#include <math.h>

// Problem constants
#define BB 16
#define NN 80
#define DH_ 384
#define LDH 1664   // Hcat row stride: [H0 | H1 | H2 | fused]

typedef unsigned int uint;
typedef unsigned long long u64;
typedef __attribute__((ext_vector_type(8))) short short8;
typedef __attribute__((ext_vector_type(4))) float f32x4;

// ---- bf16 pack helpers (RNE) ----
__device__ __forceinline__ uint packbf(float lo, float hi)
{
    uint a = __float_as_uint(lo);
    a = (a + 0x7fffu + ((a >> 16) & 1u)) >> 16;
    uint b = __float_as_uint(hi);
    b = (b + 0x7fffu + ((b >> 16) & 1u)) & 0xffff0000u;
    return a | b;
}
__device__ __forceinline__ float bflo(uint u) { return __uint_as_float(u << 16); }
__device__ __forceinline__ float bfhi(uint u) { return __uint_as_float(u & 0xffff0000u); }
__device__ __forceinline__ unsigned short cvt1(float f)
{
    uint a = __float_as_uint(f);
    return (unsigned short)((a + 0x7fffu + ((a >> 16) & 1u)) >> 16);
}

// ---------------------------------------------------------------------------
// bf16 MFMA GEMM (unchanged from round 11 — verified).
// ---------------------------------------------------------------------------
__global__ __launch_bounds__(256)
void gemm_mfma(const float* __restrict__ A, int lda,
               const unsigned short* __restrict__ W, int ldw,
               const float* __restrict__ bias,
               float* __restrict__ C, int ldc,
               int K, int act, int accum)
{
    __shared__ __attribute__((aligned(16))) unsigned short As[4096];
    __shared__ __attribute__((aligned(16))) unsigned short Bs[4096];
    const int t = threadIdx.x;
    const int lane = t & 63, wave = t >> 6;
    const int r0 = blockIdx.y * 64, o0 = blockIdx.x * 64;

    f32x4 acc0 = {0.f, 0.f, 0.f, 0.f};
    f32x4 acc1 = acc0, acc2 = acc0, acc3 = acc0;

    const int srow = t >> 2;
    const int scp = (t & 3) * 2;
    const int sw0 = ((scp ^ (srow & 7))) * 8;
    const int sw1 = (((scp + 1) ^ (srow & 7))) * 8;
    const float* ap0 = A + (size_t)(r0 + srow) * lda + scp * 8;
    const unsigned short* bp0 = W + (size_t)(o0 + srow) * ldw + scp * 8;

    const int fr = lane & 15, kg = lane >> 4;
    const int fsw = fr & 7;
    const int arow = (wave * 16 + fr) * 64;

    for (int kb = 0; kb < K; kb += 64) {
        float4 a0 = *(const float4*)(ap0 + kb);
        float4 a1 = *(const float4*)(ap0 + kb + 4);
        float4 a2 = *(const float4*)(ap0 + kb + 8);
        float4 a3 = *(const float4*)(ap0 + kb + 12);
        uint4 b0 = *(const uint4*)(bp0 + kb);
        uint4 b1 = *(const uint4*)(bp0 + kb + 8);
        uint4 apk0, apk1;
        apk0.x = packbf(a0.x, a0.y); apk0.y = packbf(a0.z, a0.w);
        apk0.z = packbf(a1.x, a1.y); apk0.w = packbf(a1.z, a1.w);
        apk1.x = packbf(a2.x, a2.y); apk1.y = packbf(a2.z, a2.w);
        apk1.z = packbf(a3.x, a3.y); apk1.w = packbf(a3.z, a3.w);
        *(uint4*)&As[srow * 64 + sw0] = apk0;
        *(uint4*)&As[srow * 64 + sw1] = apk1;
        *(uint4*)&Bs[srow * 64 + sw0] = b0;
        *(uint4*)&Bs[srow * 64 + sw1] = b1;
        __syncthreads();
#pragma unroll
        for (int h = 0; h < 2; ++h) {
            int ach = kg + 4 * h;
            short8 af = *(const short8*)&As[arow + ((ach ^ fsw)) * 8];
            short8 bf0 = *(const short8*)&Bs[(0 * 16 + fr) * 64 + ((ach ^ fsw)) * 8];
            short8 bf1 = *(const short8*)&Bs[(1 * 16 + fr) * 64 + ((ach ^ fsw)) * 8];
            short8 bf2 = *(const short8*)&Bs[(2 * 16 + fr) * 64 + ((ach ^ fsw)) * 8];
            short8 bf3 = *(const short8*)&Bs[(3 * 16 + fr) * 64 + ((ach ^ fsw)) * 8];
            acc0 = __builtin_amdgcn_mfma_f32_16x16x32_bf16(af, bf0, acc0, 0, 0, 0);
            acc1 = __builtin_amdgcn_mfma_f32_16x16x32_bf16(af, bf1, acc1, 0, 0, 0);
            acc2 = __builtin_amdgcn_mfma_f32_16x16x32_bf16(af, bf2, acc2, 0, 0, 0);
            acc3 = __builtin_amdgcn_mfma_f32_16x16x32_bf16(af, bf3, acc3, 0, 0, 0);
        }
        __syncthreads();
    }
    const int rg = lane >> 4;
    f32x4 av[4] = {acc0, acc1, acc2, acc3};
#pragma unroll
    for (int c = 0; c < 4; ++c) {
        int col = o0 + c * 16 + fr;
        float bv = bias ? bias[col] : 0.f;
#pragma unroll
        for (int r = 0; r < 4; ++r) {
            int row = r0 + wave * 16 + rg * 4 + r;
            float v = av[c][r] + bv;
            if (accum) v += C[(size_t)row * ldc + col];
            if (act == 1) v = fmaxf(v, 0.f);
            else if (act == 2) v = 1.f / (1.f + expf(-v));
            else if (act == 3 && col < 512) v = 1.f / (1.f + expf(-v));
            C[(size_t)row * ldc + col] = v;
        }
    }
}

// Convert all GEMM weights to one bf16 buffer (+ gPre bias extraction).
__global__ void wcvt(const float* __restrict__ U1, const float* __restrict__ V1,
                     const float* __restrict__ U2, const float* __restrict__ V2,
                     const float* __restrict__ Pw, const float* __restrict__ fc1w,
                     const float* __restrict__ cwi, const float* __restrict__ pwh,
                     const float* __restrict__ w0, const float* __restrict__ w1,
                     const float* __restrict__ cbi, const float* __restrict__ pbh,
                     unsigned short* __restrict__ wB, float* __restrict__ gb_)
{
    int idx = blockIdx.x * 256 + threadIdx.x;
    if (idx < 4587520) {
        float v;
        if      (idx < 524288)  v = U1[idx];
        else if (idx < 1048576) v = V1[idx - 524288];
        else if (idx < 1310720) v = U2[idx - 1048576];
        else if (idx < 1572864) v = V2[idx - 1310720];
        else if (idx < 1835008) v = Pw[idx - 1572864];
        else if (idx < 2031616) v = fc1w[idx - 1835008];
        else if (idx < 2473984) v = cwi[idx - 2031616];
        else if (idx < 2916352) v = pwh[idx - 2473984];
        else if (idx < 3358720) v = cwi[442368 + idx - 2916352];
        else if (idx < 3801088) v = pwh[442368 + idx - 3358720];
        else if (idx < 4440064) v = w0[idx - 3801088];
        else                    v = w1[idx - 4440064];
        wB[idx] = cvt1(v);
    } else if (idx < 4592128) {
        int j = idx - 4587520;
        int l = j / 2304, o = j % 2304;
        gb_[j] = (o < 1152) ? cbi[l * 1152 + o] : pbh[l * 1152 + o - 1152];
    }
}

// c_ = T1[:, :512]*T2[:, :512] -> CBuf ; Hcat fused col = V1+V2 partial sums
__global__ void ew2(const float* __restrict__ T1, const float* __restrict__ T2,
                    float* __restrict__ CBuf, float* __restrict__ Hc)
{
    int idx = blockIdx.x * 256 + threadIdx.x;  // < 655360
    int r = idx >> 9, c = idx & 511;
    CBuf[idx] = T1[r * 1024 + c] * T2[r * 1024 + c];
    Hc[r * LDH + 1152 + c] = T1[r * 1024 + 512 + c] + T2[r * 1024 + 512 + c];
}

// WgPk[l][g][k=384][cp=72]: packed bf16 pair for gate cols c=2cp, 2cp+1
__global__ void trans_wg3(const float* __restrict__ cwh, const float* __restrict__ pwi,
                          uint* __restrict__ WgPk)
{
    int idx = blockIdx.x * 256 + threadIdx.x;  // < 884736
    int l = idx / 442368;
    int r = idx % 442368;
    int g = r / 27648;
    int r2 = r % 27648;
    int k = r2 / 72, cp = r2 % 72;
    float v[2];
#pragma unroll
    for (int u = 0; u < 2; ++u) {
        int c = 2 * cp + u;
        int idx6 = c / 24, o = c % 24, d = g * 24 + o;
        v[u] = (idx6 < 3) ? cwh[l * 442368 + (idx6 * 384 + d) * 384 + k]
                          : pwi[l * 442368 + ((idx6 - 3) * 384 + d) * 384 + k];
    }
    WgPk[idx] = packbf(v[0], v[1]);
}

// WrPk[l][g][k=384][dl=24]: packed bf16 (Wr0[g*24+dl][k], Wr1[g*24+dl][k])
__global__ void trans_wr3(const float* __restrict__ Wr0, const float* __restrict__ Wr1,
                          uint* __restrict__ WrPk)
{
    int idx = blockIdx.x * 256 + threadIdx.x;  // < 294912
    int l = idx / 147456;
    int r = idx % 147456;
    int g = r / 9216;
    int r2 = r % 9216;
    int k = r2 / 24, dl = r2 % 24;
    int row = g * 24 + dl;
    float w0 = Wr0[l * 147456 + row * 384 + k];
    float w1 = Wr1[l * 147456 + row * 384 + k];
    WrPk[idx] = packbf(w0, w1);
}

// q[row] = dot(Hc[row, hin:hin+384], wq)
__global__ __launch_bounds__(256)
void qpre_k(const float* __restrict__ Hc, int hin, const float* __restrict__ wq,
            float* __restrict__ q)
{
    int wave = threadIdx.x >> 6, lane = threadIdx.x & 63;
    int row = blockIdx.x * 4 + wave;   // < 1280
    const float* hp = Hc + row * LDH + hin;
    float s = 0.f;
#pragma unroll
    for (int u = 0; u < 6; ++u) s = fmaf(hp[lane + 64 * u], wq[lane + 64 * u], s);
#pragma unroll
    for (int m = 1; m < 64; m <<= 1) s += __shfl_xor(s, m);
    if (lane == 0) q[row] = s;
}

// ---- exchange primitives: 8B aligned relaxed agent-scope atomics ONLY ----
#define ALD64(p)    __hip_atomic_load((p), __ATOMIC_RELAXED, __HIP_MEMORY_SCOPE_AGENT)
#define AST64(p, v) __hip_atomic_store((p), (v), __ATOMIC_RELAXED, __HIP_MEMORY_SCOPE_AGENT)

// ---------------------------------------------------------------------------
// Sliced scan v11: v10 protocol with
//  (1) bf16-packed M exchange (X1: 12 u64/WG, one 128B line — like X2),
//  (2) wave-specialized arrival phase: wave 0 gathers kv via shuffle-reduce
//      and runs the masked softmax WHILE waves 1-3 spin/decode h — softmax
//      and kv-gather leave the critical path; one barrier removed.
// X1: [16 b][2 slot][16 g][16 u64]: j<12 M bf16 pairs (dims 2j,2j+1).
// X2: [16 b][2 slot][16 g][16 u64]: j<12 h bf16 pairs, j=12 kv partial.
// ---------------------------------------------------------------------------
__global__ __launch_bounds__(512)
void scan11(float* Hc, int hin, int hout,
            const float* __restrict__ gPre,
            const uint* __restrict__ WrPkl,   // [16][384][24]
            const uint* __restrict__ WgPkl,   // [16][384][72]
            const float* __restrict__ qpre,
            const float* __restrict__ gatwl,
            const float* __restrict__ gatbl,
            const int* __restrict__ adj,
            const int* __restrict__ smask,
            const float* __restrict__ cbh,
            const float* __restrict__ pbi,
            u64* __restrict__ X1,             // [16 b][2 slot][256]
            u64* __restrict__ X2)             // [16 b][2 slot][256]
{
    const int b = blockIdx.x >> 4, g = blockIdx.x & 15;
    const int t = threadIdx.x;

    extern __shared__ uint WgL[];    // [384][72] packed, 110592 B
    __shared__ uint WrL[384 * 25];   // padded stride 25
    __shared__ uint Pc16[NN][25];    // packed (P0,P1), padded
    __shared__ float kvS[NN];
    __shared__ float2 ws01[NN];
    __shared__ float Mv[DH_];
    __shared__ float uA[864];        // hrow[384] / gate partials / gp+x handoff
    __shared__ float gs[144];

    {   // preload packed weights into LDS
        const uint* src = WgPkl + g * 27648;
        for (int idx = t; idx < 27648; idx += 512) WgL[idx] = src[idx];
        const uint* src2 = WrPkl + g * 9216;
        for (int idx = t; idx < 9216; idx += 512) {
            int k = idx / 24, dl = idx % 24;
            WrL[k * 25 + dl] = src2[idx];
        }
    }
    __syncthreads();

    u64* X1b = X1 + b * 512;     // 2 slots x 256
    u64* X2b = X2 + b * 512;     // 2 slots x 256
    const float gb = gatbl[0];

    int ca0 = 0, cs0 = 0, ca1 = 0, cs1 = 0;
    float cq = 0.f;
    int na0 = 0, ns0 = 0, na1 = 0, ns1 = 0;
    float nq = 0.f;
    float gpv = 0.f, xv = 0.f;

    for (int i = 0; i < NN; ++i) {
        const int rowi = b * NN + i;

        // ---- A. issue prefetches (registers; consumed later this step)
        if (t < 144) gpv = gPre[rowi * 2304 + (t / 24) * 384 + g * 24 + (t % 24)];
        else if (t < 168) xv = Hc[rowi * LDH + hin + g * 24 + (t - 144)];
        if (t < 64) {
            int ip = (i + 1 < NN) ? (i + 1) : (NN - 1);
            int rp = b * NN + ip;
            na0 = adj[rp * NN + t];
            ns0 = smask[rp * NN + t];
            if (t + 64 < NN) { na1 = adj[rp * NN + t + 64]; ns1 = smask[rp * NN + t + 64]; }
            nq = qpre[rp];
        }
        // WAR guard: prior step's phase I readers of uA finish before B writes
        __syncthreads();

        if (i > 0) {
            const u64* Xs2 = X2b + ((i - 1) & 1) * 256;
            // ---- B. wave 0: kv gather + softmax; waves 1-3: h spin/decode
            if (t < 64) {
                float kvnew = 0.f;
                if (t < 16) {
                    u64 w;
                    do { w = ALD64(&Xs2[t * 16 + 12]); } while ((uint)(w >> 32) != (uint)i);
                    kvnew = __uint_as_float((uint)w);
                }
#pragma unroll
                for (int m = 1; m < 64; m <<= 1) kvnew += __shfl_xor(kvnew, m);
                if (t == 0) kvS[i - 1] = kvnew;   // for future steps (same wave)
                // masked softmax using prefetched adj/smask/q + kvnew
                float q = cq + gb;
                int j0 = t, j1 = t + 64;
                float a0v = -1e30f, a1v = -1e30f;
                if (j0 < i && ca0 != 0) a0v = q + ((j0 == i - 1) ? kvnew : kvS[j0]);
                if (j1 < i && ca1 != 0) a1v = q + ((j1 == i - 1) ? kvnew : kvS[j1]);
                float mx = fmaxf(a0v, a1v);
#pragma unroll
                for (int m = 1; m < 64; m <<= 1) mx = fmaxf(mx, __shfl_xor(mx, m));
                float e0 = expf(a0v - mx);
                float e1 = (j1 < NN) ? expf(a1v - mx) : 0.f;
                float ss = e0 + e1;
#pragma unroll
                for (int m = 1; m < 64; m <<= 1) ss += __shfl_xor(ss, m);
                float inv = 1.f / ss;
                float w0 = e0 * inv;
                float s0 = (float)cs0;
                ws01[j0] = make_float2(w0 * s0, w0 - w0 * s0);
                if (j1 < NN) {
                    float w1 = e1 * inv;
                    float s1 = (float)cs1;
                    ws01[j1] = make_float2(w1 * s1, w1 - w1 * s1);
                }
            } else if (t < 256) {
                int idx = t - 64;            // 0..191
                int gg = idx / 12, j = idx % 12;
                u64 w;
                do { w = ALD64(&Xs2[gg * 16 + j]); } while ((uint)(w >> 32) != (uint)i);
                uint lo = (uint)w;
                uA[gg * 24 + 2 * j]     = bflo(lo);
                uA[gg * 24 + 2 * j + 1] = bfhi(lo);
            }
            __syncthreads();

            // ---- C. P-update for row i-1 (LDS bf16 weights, h in uA)
            if (t < 384) {
                int dl0 = t >> 4, sub = t & 15, part = sub & 7, half = sub >> 3;
                float acc = 0.f;
#pragma unroll 8
                for (int m = 0; m < 48; ++m) {
                    int k = part + 8 * m;
                    uint u = WrL[k * 25 + dl0];
                    float w2_ = half ? bfhi(u) : bflo(u);
                    acc = fmaf(w2_, uA[k], acc);
                }
                acc += __shfl_xor(acc, 1);
                acc += __shfl_xor(acc, 2);
                acc += __shfl_xor(acc, 4);
                float other = __shfl_xor(acc, 8);
                if (sub == 0) Pc16[i - 1][dl0] = packbf(acc, other);
            }
            __syncthreads();

            // ---- E. M slice -> own X1 line (bf16 pairs, seq i+1 embedded)
            u64* Xs1 = X1b + (i & 1) * 256;
            if (t < 384) {
                int dl0 = t >> 4, sub = t & 15, lane6 = t & 63;
                float acc = 0.f;
                for (int j = sub; j < i; j += 16) {
                    uint u = Pc16[j][dl0];
                    float2 w2_ = ws01[j];
                    acc = fmaf(w2_.x, bflo(u), acc);
                    acc = fmaf(w2_.y, bfhi(u), acc);
                }
                acc += __shfl_xor(acc, 1);
                acc += __shfl_xor(acc, 2);
                acc += __shfl_xor(acc, 4);
                acc += __shfl_xor(acc, 8);
                float hi = __shfl(acc, (lane6 + 16) & 63);
                if (sub == 0 && !(dl0 & 1))
                    AST64(&Xs1[g * 16 + (dl0 >> 1)],
                          ((u64)(uint)(i + 1) << 32) | (u64)packbf(acc, hi));
            }

            // ---- F. per-thread spin for full M (bf16), exact seq == i+1
            if (t < 192) {
                int gg = t / 12, j = t % 12;
                u64 wm;
                do { wm = ALD64(&Xs1[gg * 16 + j]); } while ((uint)(wm >> 32) != (uint)(i + 1));
                uint lo = (uint)wm;
                Mv[gg * 24 + 2 * j]     = bflo(lo);
                Mv[gg * 24 + 2 * j + 1] = bfhi(lo);
            }
            __syncthreads();
        } else {
            if (t < 384) Mv[t] = 0.f;
            __syncthreads();
        }

        // rotate softmax prefetch registers (used at step i+1)
        if (t < 64) { ca0 = na0; cs0 = ns0; ca1 = na1; cs1 = ns1; cq = nq; }

        // ---- G. gate slice from LDS bf16: 144 outputs = 72 pairs x 6 k-chunks
        if (t < 432) {
            int cp = t % 72, kt = t / 72;
            int kbase = kt * 64;
            float a0 = 0.f, a1 = 0.f;
#pragma unroll 8
            for (int kk = 0; kk < 64; ++kk) {
                uint u = WgL[(kbase + kk) * 72 + cp];
                float m = Mv[kbase + kk];
                a0 = fmaf(bflo(u), m, a0);
                a1 = fmaf(bfhi(u), m, a1);
            }
            uA[kt * 144 + 2 * cp] = a0;
            uA[kt * 144 + 2 * cp + 1] = a1;
        }
        __syncthreads();
        if (t < 144) {
            float s = 0.f;
#pragma unroll
            for (int kt = 0; kt < 6; ++kt) s += uA[kt * 144 + t];
            gs[t] = s;
        }
        __syncthreads();

        // ---- H. hand off prefetched gp/x registers into (now free) uA
        if (t < 144) uA[t] = gpv;
        else if (t < 168) uA[t] = xv;
        __syncthreads();

        // ---- I. GRU cells for 24 dims -> Hc + own X2 line (bf16 pairs)
        u64* Xs2w = X2b + (i & 1) * 256;
        if (t < 32) {
            float kp = 0.f, h = 0.f;
            if (t < 24) {
                int dg = g * 24 + t;
                float m = Mv[dg];
                float gir = uA[t], giz = uA[24 + t], gin = uA[48 + t];
                float ghr = gs[t] + cbh[dg];
                float ghz = gs[24 + t] + cbh[384 + dg];
                float ghn = gs[48 + t] + cbh[768 + dg];
                float r = 1.f / (1.f + expf(-(gir + ghr)));
                float z = 1.f / (1.f + expf(-(giz + ghz)));
                float n = tanhf(gin + r * ghn);
                float Cc = (1.f - z) * n + z * m;
                float pir = gs[72 + t] + pbi[dg];
                float piz = gs[96 + t] + pbi[384 + dg];
                float pin = gs[120 + t] + pbi[768 + dg];
                float phr = uA[72 + t], phz = uA[96 + t], phn = uA[120 + t];
                float r2 = 1.f / (1.f + expf(-(pir + phr)));
                float z2 = 1.f / (1.f + expf(-(piz + phz)));
                float n2 = tanhf(pin + r2 * phn);
                float x = uA[144 + t];
                float Pp = (1.f - z2) * n2 + z2 * x;
                h = Cc + Pp;
                Hc[rowi * LDH + hout + dg] = h;
                kp = h * gatwl[384 + dg];
            }
            int src = (t < 12) ? 2 * t : 0;
            float ha = __shfl(h, src);
            float hb = __shfl(h, src + 1);
            if (t < 12)
                AST64(&Xs2w[g * 16 + t],
                      ((u64)(uint)(i + 1) << 32) | (u64)packbf(ha, hb));
#pragma unroll
            for (int m = 16; m >= 1; m >>= 1) kp += __shfl_down(kp, m);
            if (t == 0)
                AST64(&Xs2w[g * 16 + 12],
                      ((u64)(uint)(i + 1) << 32) | (u64)__float_as_uint(kp));
        }
        // loop-top barrier orders uA reuse; spins order X.
    }
}

// logits (7) + log_softmax, one wave per row
__global__ __launch_bounds__(256)
void mlp_final(const float* __restrict__ h, const float* __restrict__ w2,
               const float* __restrict__ b2, float* __restrict__ out)
{
    int wave = threadIdx.x >> 6, lane = threadIdx.x & 63;
    int r = blockIdx.x * 4 + wave;   // < 1280
    float hreg[6];
#pragma unroll
    for (int m = 0; m < 6; ++m) hreg[m] = h[r * 384 + lane + 64 * m];
    float logit[7];
#pragma unroll
    for (int c = 0; c < 7; ++c) {
        float s = 0.f;
#pragma unroll
        for (int m = 0; m < 6; ++m)
            s = fmaf(hreg[m], w2[c * 384 + lane + 64 * m], s);
#pragma unroll
        for (int m = 1; m < 64; m <<= 1) s += __shfl_xor(s, m);
        logit[c] = s + b2[c];
    }
    float mx = logit[0];
#pragma unroll
    for (int c = 1; c < 7; ++c) mx = fmaxf(mx, logit[c]);
    float se = 0.f;
#pragma unroll
    for (int c = 0; c < 7; ++c) se += expf(logit[c] - mx);
    float lse = mx + logf(se);
    if (lane < 7) out[r * 7 + lane] = logit[lane] - lse;
}

extern "C" void kernel_launch(void* const* d_in, const int* in_sizes, int n_in,
                              void* d_out, int out_size, void* d_ws, size_t ws_size,
                              hipStream_t stream)
{
    const float* ftext = (const float*)d_in[0];
    const float* faud  = (const float*)d_in[1];
    const int*   adj   = (const int*)d_in[2];
    const int*   smask = (const int*)d_in[3];
    const float* U1    = (const float*)d_in[6];
    const float* U2    = (const float*)d_in[7];
    const float* Pw    = (const float*)d_in[8];
    const float* Pb    = (const float*)d_in[9];
    const float* V1    = (const float*)d_in[10];
    const float* V2    = (const float*)d_in[11];
    const float* fc1w  = (const float*)d_in[12];
    const float* fc1b  = (const float*)d_in[13];
    const float* gatw  = (const float*)d_in[14];
    const float* gatb  = (const float*)d_in[15];
    const float* Wr0   = (const float*)d_in[16];
    const float* Wr1   = (const float*)d_in[17];
    const float* cwi   = (const float*)d_in[18];
    const float* cwh   = (const float*)d_in[19];
    const float* cbi   = (const float*)d_in[20];
    const float* cbh   = (const float*)d_in[21];
    const float* pwi   = (const float*)d_in[22];
    const float* pwh   = (const float*)d_in[23];
    const float* pbi   = (const float*)d_in[24];
    const float* pbh   = (const float*)d_in[25];
    const float* w0    = (const float*)d_in[26];
    const float* b0    = (const float*)d_in[27];
    const float* w1    = (const float*)d_in[28];
    const float* b1    = (const float*)d_in[29];
    const float* w2    = (const float*)d_in[30];
    const float* b2    = (const float*)d_in[31];
    float* out = (float*)d_out;
    float* ws = (float*)d_ws;

    // workspace layout (f32 words)
    float* Hcat  = ws;                        // 2,129,920
    float* gPre  = ws + 2129920;              // 2,949,120 (front: T1|T2; back: h2)
    float* T1b   = gPre;                      // 1,310,720
    float* T2b   = gPre + 1310720;            // 1,310,720
    float* CBuf  = ws + 5079040;              // 655,360 (later h1)
    uint*  WgPk  = (uint*)(ws + 5734400);     // 884,736 u32
    uint*  WrPk  = (uint*)(ws + 6619136);     // 294,912 u32
    float* gb_   = ws + 6914048;              // 4,608
    float* qpreB = ws + 6918656;              // 2,560
    u64*   X1l0  = (u64*)(ws + 6921216);      // 8,192 u64
    u64*   X2l0  = X1l0 + 8192;               // 8,192 u64
    u64*   X1l1  = X2l0 + 8192;               // 8,192 u64
    u64*   X2l1  = X1l1 + 8192;               // 8,192 u64
    unsigned short* wB = (unsigned short*)(ws + 7019520);  // 4,587,520 u16

    auto g = [&](const float* A, int lda, size_t woff, int ldw,
                 const float* bias, float* C, int ldc, int K, int N,
                 int act, int accum) {
        dim3 grid(N / 64, 1280 / 64);
        gemm_mfma<<<grid, 256, 0, stream>>>(A, lda, wB + woff, ldw, bias, C, ldc,
                                            K, act, accum);
    };

    // zero ALL exchange words each launch (kills cross-launch seq aliasing)
    hipMemsetAsync(X1l0, 0, (size_t)4 * 8192 * sizeof(u64), stream);

    // weight prep (independent of front-end)
    wcvt<<<17938, 256, 0, stream>>>(U1, V1, U2, V2, Pw, fc1w, cwi, pwh, w0, w1,
                                    cbi, pbh, wB, gb_);
    trans_wg3<<<3456, 256, 0, stream>>>(cwh, pwi, WgPk);
    trans_wr3<<<1152, 256, 0, stream>>>(Wr0, Wr1, WrPk);

    // Front-end fusion (bf16 MFMA)
    g(ftext, 1024, 0, 1024, nullptr, T1b, 1024, 1024, 1024, 3, 0);
    g(faud, 512, 1048576, 512, nullptr, T2b, 1024, 512, 1024, 3, 0);
    ew2<<<2560, 256, 0, stream>>>(T1b, T2b, CBuf, Hcat);
    g(CBuf, 512, 1572864, 512, Pb, Hcat + 1152, LDH, 512, 512, 0, 1);      // fused
    g(Hcat + 1152, LDH, 1835008, 512, fc1b, Hcat, LDH, 512, 384, 1, 0);    // H0

    // Two GAT/GRU layers
    for (int l = 0; l < 2; ++l) {
        g(Hcat + l * 384, LDH, 2031616 + (size_t)l * 884736, 384,
          gb_ + l * 2304, gPre, 2304, 384, 2304, 0, 0);
        qpre_k<<<320, 256, 0, stream>>>(Hcat, l * 384, gatw + l * 768, qpreB + l * 1280);
        scan11<<<256, 512, 110592, stream>>>(Hcat, l * 384, (l + 1) * 384, gPre,
                                             WrPk + l * 147456, WgPk + l * 442368,
                                             qpreB + l * 1280, gatw + l * 768, gatb + l,
                                             adj, smask, cbh + l * 1152, pbi + l * 1152,
                                             l ? X1l1 : X1l0, l ? X2l1 : X2l0);
    }

    // Back-end MLP + log_softmax (bf16 MFMA)
    g(Hcat, LDH, 3801088, 1664, b0, CBuf, 384, 1664, 384, 1, 0);   // h1
    g(CBuf, 384, 4440064, 384, b1, gPre, 384, 384, 384, 1, 0);     // h2
    mlp_final<<<320, 256, 0, stream>>>(gPre, w2, b2, out);
}

// Round 13
// 1150.949 us; speedup vs baseline: 1.0790x; 1.0790x over previous
//
#include <hip/hip_runtime.h>
#include <hip/hip_bf16.h>
#include <math.h>

// Problem constants
#define BB 16
#define NN 80
#define DH_ 384
#define LDH 1664   // Hcat row stride: [H0 | H1 | H2 | fused]

typedef unsigned int uint;
typedef unsigned long long u64;
typedef __attribute__((ext_vector_type(8))) short short8;
typedef __attribute__((ext_vector_type(4))) float f32x4;

// ---- bf16 pack helpers (RNE) ----
__device__ __forceinline__ uint packbf(float lo, float hi)
{
    uint a = __float_as_uint(lo);
    a = (a + 0x7fffu + ((a >> 16) & 1u)) >> 16;
    uint b = __float_as_uint(hi);
    b = (b + 0x7fffu + ((b >> 16) & 1u)) & 0xffff0000u;
    return a | b;
}
__device__ __forceinline__ float bflo(uint u) { return __uint_as_float(u << 16); }
__device__ __forceinline__ float bfhi(uint u) { return __uint_as_float(u & 0xffff0000u); }
__device__ __forceinline__ unsigned short cvt1(float f)
{
    uint a = __float_as_uint(f);
    return (unsigned short)((a + 0x7fffu + ((a >> 16) & 1u)) >> 16);
}

// ---------------------------------------------------------------------------
// bf16 MFMA GEMM (round-11 verified).
// ---------------------------------------------------------------------------
__global__ __launch_bounds__(256)
void gemm_mfma(const float* __restrict__ A, int lda,
               const unsigned short* __restrict__ W, int ldw,
               const float* __restrict__ bias,
               float* __restrict__ C, int ldc,
               int K, int act, int accum)
{
    __shared__ __attribute__((aligned(16))) unsigned short As[4096];
    __shared__ __attribute__((aligned(16))) unsigned short Bs[4096];
    const int t = threadIdx.x;
    const int lane = t & 63, wave = t >> 6;
    const int r0 = blockIdx.y * 64, o0 = blockIdx.x * 64;

    f32x4 acc0 = {0.f, 0.f, 0.f, 0.f};
    f32x4 acc1 = acc0, acc2 = acc0, acc3 = acc0;

    const int srow = t >> 2;
    const int scp = (t & 3) * 2;
    const int sw0 = ((scp ^ (srow & 7))) * 8;
    const int sw1 = (((scp + 1) ^ (srow & 7))) * 8;
    const float* ap0 = A + (size_t)(r0 + srow) * lda + scp * 8;
    const unsigned short* bp0 = W + (size_t)(o0 + srow) * ldw + scp * 8;

    const int fr = lane & 15, kg = lane >> 4;
    const int fsw = fr & 7;
    const int arow = (wave * 16 + fr) * 64;

    for (int kb = 0; kb < K; kb += 64) {
        float4 a0 = *(const float4*)(ap0 + kb);
        float4 a1 = *(const float4*)(ap0 + kb + 4);
        float4 a2 = *(const float4*)(ap0 + kb + 8);
        float4 a3 = *(const float4*)(ap0 + kb + 12);
        uint4 b0 = *(const uint4*)(bp0 + kb);
        uint4 b1 = *(const uint4*)(bp0 + kb + 8);
        uint4 apk0, apk1;
        apk0.x = packbf(a0.x, a0.y); apk0.y = packbf(a0.z, a0.w);
        apk0.z = packbf(a1.x, a1.y); apk0.w = packbf(a1.z, a1.w);
        apk1.x = packbf(a2.x, a2.y); apk1.y = packbf(a2.z, a2.w);
        apk1.z = packbf(a3.x, a3.y); apk1.w = packbf(a3.z, a3.w);
        *(uint4*)&As[srow * 64 + sw0] = apk0;
        *(uint4*)&As[srow * 64 + sw1] = apk1;
        *(uint4*)&Bs[srow * 64 + sw0] = b0;
        *(uint4*)&Bs[srow * 64 + sw1] = b1;
        __syncthreads();
#pragma unroll
        for (int h = 0; h < 2; ++h) {
            int ach = kg + 4 * h;
            short8 af = *(const short8*)&As[arow + ((ach ^ fsw)) * 8];
            short8 bf0 = *(const short8*)&Bs[(0 * 16 + fr) * 64 + ((ach ^ fsw)) * 8];
            short8 bf1 = *(const short8*)&Bs[(1 * 16 + fr) * 64 + ((ach ^ fsw)) * 8];
            short8 bf2 = *(const short8*)&Bs[(2 * 16 + fr) * 64 + ((ach ^ fsw)) * 8];
            short8 bf3 = *(const short8*)&Bs[(3 * 16 + fr) * 64 + ((ach ^ fsw)) * 8];
            acc0 = __builtin_amdgcn_mfma_f32_16x16x32_bf16(af, bf0, acc0, 0, 0, 0);
            acc1 = __builtin_amdgcn_mfma_f32_16x16x32_bf16(af, bf1, acc1, 0, 0, 0);
            acc2 = __builtin_amdgcn_mfma_f32_16x16x32_bf16(af, bf2, acc2, 0, 0, 0);
            acc3 = __builtin_amdgcn_mfma_f32_16x16x32_bf16(af, bf3, acc3, 0, 0, 0);
        }
        __syncthreads();
    }
    const int rg = lane >> 4;
    f32x4 av[4] = {acc0, acc1, acc2, acc3};
#pragma unroll
    for (int c = 0; c < 4; ++c) {
        int col = o0 + c * 16 + fr;
        float bv = bias ? bias[col] : 0.f;
#pragma unroll
        for (int r = 0; r < 4; ++r) {
            int row = r0 + wave * 16 + rg * 4 + r;
            float v = av[c][r] + bv;
            if (accum) v += C[(size_t)row * ldc + col];
            if (act == 1) v = fmaxf(v, 0.f);
            else if (act == 2) v = 1.f / (1.f + expf(-v));
            else if (act == 3 && col < 512) v = 1.f / (1.f + expf(-v));
            C[(size_t)row * ldc + col] = v;
        }
    }
}

// Convert all GEMM weights to one bf16 buffer (+ gPre bias extraction).
__global__ void wcvt(const float* __restrict__ U1, const float* __restrict__ V1,
                     const float* __restrict__ U2, const float* __restrict__ V2,
                     const float* __restrict__ Pw, const float* __restrict__ fc1w,
                     const float* __restrict__ cwi, const float* __restrict__ pwh,
                     const float* __restrict__ w0, const float* __restrict__ w1,
                     const float* __restrict__ cbi, const float* __restrict__ pbh,
                     unsigned short* __restrict__ wB, float* __restrict__ gb_)
{
    int idx = blockIdx.x * 256 + threadIdx.x;
    if (idx < 4587520) {
        float v;
        if      (idx < 524288)  v = U1[idx];
        else if (idx < 1048576) v = V1[idx - 524288];
        else if (idx < 1310720) v = U2[idx - 1048576];
        else if (idx < 1572864) v = V2[idx - 1310720];
        else if (idx < 1835008) v = Pw[idx - 1572864];
        else if (idx < 2031616) v = fc1w[idx - 1835008];
        else if (idx < 2473984) v = cwi[idx - 2031616];
        else if (idx < 2916352) v = pwh[idx - 2473984];
        else if (idx < 3358720) v = cwi[442368 + idx - 2916352];
        else if (idx < 3801088) v = pwh[442368 + idx - 3358720];
        else if (idx < 4440064) v = w0[idx - 3801088];
        else                    v = w1[idx - 4440064];
        wB[idx] = cvt1(v);
    } else if (idx < 4592128) {
        int j = idx - 4587520;
        int l = j / 2304, o = j % 2304;
        gb_[j] = (o < 1152) ? cbi[l * 1152 + o] : pbh[l * 1152 + o - 1152];
    }
}

// c_ = T1[:, :512]*T2[:, :512] -> CBuf ; Hcat fused col = V1+V2 partial sums
__global__ void ew2(const float* __restrict__ T1, const float* __restrict__ T2,
                    float* __restrict__ CBuf, float* __restrict__ Hc)
{
    int idx = blockIdx.x * 256 + threadIdx.x;  // < 655360
    int r = idx >> 9, c = idx & 511;
    CBuf[idx] = T1[r * 1024 + c] * T2[r * 1024 + c];
    Hc[r * LDH + 1152 + c] = T1[r * 1024 + 512 + c] + T2[r * 1024 + 512 + c];
}

// WgPk[l][g][k=384][cp=72]: packed bf16 pair for gate cols c=2cp, 2cp+1
__global__ void trans_wg3(const float* __restrict__ cwh, const float* __restrict__ pwi,
                          uint* __restrict__ WgPk)
{
    int idx = blockIdx.x * 256 + threadIdx.x;  // < 884736
    int l = idx / 442368;
    int r = idx % 442368;
    int g = r / 27648;
    int r2 = r % 27648;
    int k = r2 / 72, cp = r2 % 72;
    float v[2];
#pragma unroll
    for (int u = 0; u < 2; ++u) {
        int c = 2 * cp + u;
        int idx6 = c / 24, o = c % 24, d = g * 24 + o;
        v[u] = (idx6 < 3) ? cwh[l * 442368 + (idx6 * 384 + d) * 384 + k]
                          : pwi[l * 442368 + ((idx6 - 3) * 384 + d) * 384 + k];
    }
    WgPk[idx] = packbf(v[0], v[1]);
}

// WrPk[l][g][k=384][dl=24]: packed bf16 (Wr0[g*24+dl][k], Wr1[g*24+dl][k])
__global__ void trans_wr3(const float* __restrict__ Wr0, const float* __restrict__ Wr1,
                          uint* __restrict__ WrPk)
{
    int idx = blockIdx.x * 256 + threadIdx.x;  // < 294912
    int l = idx / 147456;
    int r = idx % 147456;
    int g = r / 9216;
    int r2 = r % 9216;
    int k = r2 / 24, dl = r2 % 24;
    int row = g * 24 + dl;
    float w0 = Wr0[l * 147456 + row * 384 + k];
    float w1 = Wr1[l * 147456 + row * 384 + k];
    WrPk[idx] = packbf(w0, w1);
}

// q[row] = dot(Hc[row, hin:hin+384], wq)
__global__ __launch_bounds__(256)
void qpre_k(const float* __restrict__ Hc, int hin, const float* __restrict__ wq,
            float* __restrict__ q)
{
    int wave = threadIdx.x >> 6, lane = threadIdx.x & 63;
    int row = blockIdx.x * 4 + wave;   // < 1280
    const float* hp = Hc + row * LDH + hin;
    float s = 0.f;
#pragma unroll
    for (int u = 0; u < 6; ++u) s = fmaf(hp[lane + 64 * u], wq[lane + 64 * u], s);
#pragma unroll
    for (int m = 1; m < 64; m <<= 1) s += __shfl_xor(s, m);
    if (lane == 0) q[row] = s;
}

// ---- exchange primitives: 8B aligned relaxed agent-scope atomics ONLY ----
#define ALD64(p)    __hip_atomic_load((p), __ATOMIC_RELAXED, __HIP_MEMORY_SCOPE_AGENT)
#define AST64(p, v) __hip_atomic_store((p), (v), __ATOMIC_RELAXED, __HIP_MEMORY_SCOPE_AGENT)

// ---------------------------------------------------------------------------
// Sliced scan v10 (proven at 508-512 us/dispatch, no tails — rounds 10/11).
// ---------------------------------------------------------------------------
__global__ __launch_bounds__(512)
void scan10(float* Hc, int hin, int hout,
            const float* __restrict__ gPre,
            const uint* __restrict__ WrPkl,   // [16][384][24]
            const uint* __restrict__ WgPkl,   // [16][384][72]
            const float* __restrict__ qpre,
            const float* __restrict__ gatwl,
            const float* __restrict__ gatbl,
            const int* __restrict__ adj,
            const int* __restrict__ smask,
            const float* __restrict__ cbh,
            const float* __restrict__ pbi,
            u64* __restrict__ X1,             // [16 b][2 slot][512]
            u64* __restrict__ X2)             // [16 b][2 slot][256]
{
    const int wg = blockIdx.x;
    const int b = wg >> 4, g = wg & 15;
    const int t = threadIdx.x;

    extern __shared__ uint WgL[];    // [384][72] packed, 110592 B
    __shared__ uint WrL[384 * 25];   // padded stride 25
    __shared__ uint Pc16[NN][25];    // packed (P0,P1), padded
    __shared__ float kvS[NN];
    __shared__ float2 ws01[NN];
    __shared__ float Mv[DH_];
    __shared__ float uA[864];        // hrow[384] / gate partials / gp+x handoff
    __shared__ float gs[144];
    __shared__ float karr[16];

    {   // preload packed weights into LDS
        const uint* src = WgPkl + g * 27648;
        for (int idx = t; idx < 27648; idx += 512) WgL[idx] = src[idx];
        const uint* src2 = WrPkl + g * 9216;
        for (int idx = t; idx < 9216; idx += 512) {
            int k = idx / 24, dl = idx % 24;
            WrL[k * 25 + dl] = src2[idx];
        }
    }
    __syncthreads();

    u64* X1b = X1 + b * 1024;    // 2 slots x 512
    u64* X2b = X2 + b * 512;     // 2 slots x 256
    const float gb = gatbl[0];

    int ca0 = 0, cs0 = 0, ca1 = 0, cs1 = 0;
    float cq = 0.f;
    int na0 = 0, ns0 = 0, na1 = 0, ns1 = 0;
    float nq = 0.f;
    float gpv = 0.f, xv = 0.f;

    for (int i = 0; i < NN; ++i) {
        const int rowi = b * NN + i;

        // ---- A. issue prefetches (registers; consumed later this step)
        if (t < 144) gpv = gPre[rowi * 2304 + (t / 24) * 384 + g * 24 + (t % 24)];
        else if (t < 168) xv = Hc[rowi * LDH + hin + g * 24 + (t - 144)];
        if (t < 64) {
            int ip = (i + 1 < NN) ? (i + 1) : (NN - 1);
            int rp = b * NN + ip;
            na0 = adj[rp * NN + t];
            ns0 = smask[rp * NN + t];
            if (t + 64 < NN) { na1 = adj[rp * NN + t + 64]; ns1 = smask[rp * NN + t + 64]; }
            nq = qpre[rp];
        }
        __syncthreads();

        if (i > 0) {
            // ---- B. per-thread spin on X2 slot[(i-1)&1], exact seq == i
            const u64* Xs2 = X2b + ((i - 1) & 1) * 256;
            if (t < 256) {
                int gg = t >> 4, j = t & 15;
                if (j < 13) {
                    u64 w;
                    do { w = ALD64(&Xs2[gg * 16 + j]); } while ((uint)(w >> 32) != (uint)i);
                    uint lo = (uint)w;
                    if (j < 12) {
                        uA[gg * 24 + 2 * j]     = bflo(lo);
                        uA[gg * 24 + 2 * j + 1] = bfhi(lo);
                    } else {
                        karr[gg] = __uint_as_float(lo);
                    }
                }
            }
            __syncthreads();

            // ---- C. kv[i-1] scalar + P-update for row i-1 (LDS bf16 weights)
            if (t == 400) {
                float s = 0.f;
#pragma unroll
                for (int u = 0; u < 16; ++u) s += karr[u];
                kvS[i - 1] = s;
            }
            if (t < 384) {
                int dl0 = t >> 4, sub = t & 15, part = sub & 7, half = sub >> 3;
                float acc = 0.f;
#pragma unroll 8
                for (int m = 0; m < 48; ++m) {
                    int k = part + 8 * m;
                    uint u = WrL[k * 25 + dl0];
                    float w2_ = half ? bfhi(u) : bflo(u);
                    acc = fmaf(w2_, uA[k], acc);
                }
                acc += __shfl_xor(acc, 1);
                acc += __shfl_xor(acc, 2);
                acc += __shfl_xor(acc, 4);
                float other = __shfl_xor(acc, 8);
                if (sub == 0) Pc16[i - 1][dl0] = packbf(acc, other);
            }
            __syncthreads();

            // ---- D. masked softmax (wave 0) using prefetched inputs
            if (t < 64) {
                float q = cq + gb;
                int j0 = t, j1 = t + 64;
                float a0v = -1e30f, a1v = -1e30f;
                if (j0 < i && ca0 != 0) a0v = q + kvS[j0];
                if (j1 < i && ca1 != 0) a1v = q + kvS[j1];
                float mx = fmaxf(a0v, a1v);
#pragma unroll
                for (int m = 1; m < 64; m <<= 1) mx = fmaxf(mx, __shfl_xor(mx, m));
                float e0 = expf(a0v - mx);
                float e1 = (j1 < NN) ? expf(a1v - mx) : 0.f;
                float ss = e0 + e1;
#pragma unroll
                for (int m = 1; m < 64; m <<= 1) ss += __shfl_xor(ss, m);
                float inv = 1.f / ss;
                float w0 = e0 * inv;
                float s0 = (float)cs0;
                ws01[j0] = make_float2(w0 * s0, w0 - w0 * s0);
                if (j1 < NN) {
                    float w1 = e1 * inv;
                    float s1 = (float)cs1;
                    ws01[j1] = make_float2(w1 * s1, w1 - w1 * s1);
                }
            }
            __syncthreads();

            // ---- E. M slice -> own X1 segment (seq i+1; fire-and-forget)
            u64* Xs1 = X1b + (i & 1) * 512;
            if (t < 384) {
                int dl0 = t >> 4, sub = t & 15;
                float acc = 0.f;
                for (int j = sub; j < i; j += 16) {
                    uint u = Pc16[j][dl0];
                    float2 w2_ = ws01[j];
                    acc = fmaf(w2_.x, bflo(u), acc);
                    acc = fmaf(w2_.y, bfhi(u), acc);
                }
                acc += __shfl_xor(acc, 1);
                acc += __shfl_xor(acc, 2);
                acc += __shfl_xor(acc, 4);
                acc += __shfl_xor(acc, 8);
                if (sub == 0)
                    AST64(&Xs1[g * 32 + dl0],
                          ((u64)(uint)(i + 1) << 32) | (u64)__float_as_uint(acc));
            }

            // ---- F. per-thread spin for full M, exact seq == i+1
            if (t < 512) {
                int gg = t >> 5, j = t & 31;
                if (j < 24) {
                    u64 wm;
                    do { wm = ALD64(&Xs1[gg * 32 + j]); } while ((uint)(wm >> 32) != (uint)(i + 1));
                    Mv[gg * 24 + j] = __uint_as_float((uint)wm);
                }
            }
            __syncthreads();
        } else {
            if (t < 384) Mv[t] = 0.f;
            __syncthreads();
        }

        if (t < 64) { ca0 = na0; cs0 = ns0; ca1 = na1; cs1 = ns1; cq = nq; }

        // ---- G. gate slice from LDS bf16: 144 outputs = 72 pairs x 6 k-chunks
        if (t < 432) {
            int cp = t % 72, kt = t / 72;
            int kbase = kt * 64;
            float a0 = 0.f, a1 = 0.f;
#pragma unroll 8
            for (int kk = 0; kk < 64; ++kk) {
                uint u = WgL[(kbase + kk) * 72 + cp];
                float m = Mv[kbase + kk];
                a0 = fmaf(bflo(u), m, a0);
                a1 = fmaf(bfhi(u), m, a1);
            }
            uA[kt * 144 + 2 * cp] = a0;
            uA[kt * 144 + 2 * cp + 1] = a1;
        }
        __syncthreads();
        if (t < 144) {
            float s = 0.f;
#pragma unroll
            for (int kt = 0; kt < 6; ++kt) s += uA[kt * 144 + t];
            gs[t] = s;
        }
        __syncthreads();

        // ---- H. hand off prefetched gp/x registers into (now free) uA
        if (t < 144) uA[t] = gpv;
        else if (t < 168) uA[t] = xv;
        __syncthreads();

        // ---- I. GRU cells for 24 dims -> Hc + own X2 segment (bf16 pairs)
        u64* Xs2w = X2b + (i & 1) * 256;
        if (t < 32) {
            float kp = 0.f, h = 0.f;
            if (t < 24) {
                int dg = g * 24 + t;
                float m = Mv[dg];
                float gir = uA[t], giz = uA[24 + t], gin = uA[48 + t];
                float ghr = gs[t] + cbh[dg];
                float ghz = gs[24 + t] + cbh[384 + dg];
                float ghn = gs[48 + t] + cbh[768 + dg];
                float r = 1.f / (1.f + expf(-(gir + ghr)));
                float z = 1.f / (1.f + expf(-(giz + ghz)));
                float n = tanhf(gin + r * ghn);
                float Cc = (1.f - z) * n + z * m;
                float pir = gs[72 + t] + pbi[dg];
                float piz = gs[96 + t] + pbi[384 + dg];
                float pin = gs[120 + t] + pbi[768 + dg];
                float phr = uA[72 + t], phz = uA[96 + t], phn = uA[120 + t];
                float r2 = 1.f / (1.f + expf(-(pir + phr)));
                float z2 = 1.f / (1.f + expf(-(piz + phz)));
                float n2 = tanhf(pin + r2 * phn);
                float x = uA[144 + t];
                float Pp = (1.f - z2) * n2 + z2 * x;
                h = Cc + Pp;
                Hc[rowi * LDH + hout + dg] = h;
                kp = h * gatwl[384 + dg];
            }
            int src = (t < 12) ? 2 * t : 0;
            float ha = __shfl(h, src);
            float hb = __shfl(h, src + 1);
            if (t < 12)
                AST64(&Xs2w[g * 16 + t],
                      ((u64)(uint)(i + 1) << 32) | (u64)packbf(ha, hb));
#pragma unroll
            for (int m = 16; m >= 1; m >>= 1) kp += __shfl_down(kp, m);
            if (t == 0)
                AST64(&Xs2w[g * 16 + 12],
                      ((u64)(uint)(i + 1) << 32) | (u64)__float_as_uint(kp));
        }
    }
}

// logits (7) + log_softmax, one wave per row
__global__ __launch_bounds__(256)
void mlp_final(const float* __restrict__ h, const float* __restrict__ w2,
               const float* __restrict__ b2, float* __restrict__ out)
{
    int wave = threadIdx.x >> 6, lane = threadIdx.x & 63;
    int r = blockIdx.x * 4 + wave;   // < 1280
    float hreg[6];
#pragma unroll
    for (int m = 0; m < 6; ++m) hreg[m] = h[r * 384 + lane + 64 * m];
    float logit[7];
#pragma unroll
    for (int c = 0; c < 7; ++c) {
        float s = 0.f;
#pragma unroll
        for (int m = 0; m < 6; ++m)
            s = fmaf(hreg[m], w2[c * 384 + lane + 64 * m], s);
#pragma unroll
        for (int m = 1; m < 64; m <<= 1) s += __shfl_xor(s, m);
        logit[c] = s + b2[c];
    }
    float mx = logit[0];
#pragma unroll
    for (int c = 1; c < 7; ++c) mx = fmaxf(mx, logit[c]);
    float se = 0.f;
#pragma unroll
    for (int c = 0; c < 7; ++c) se += expf(logit[c] - mx);
    float lse = mx + logf(se);
    if (lane < 7) out[r * 7 + lane] = logit[lane] - lse;
}

extern "C" void kernel_launch(void* const* d_in, const int* in_sizes, int n_in,
                              void* d_out, int out_size, void* d_ws, size_t ws_size,
                              hipStream_t stream)
{
    const float* ftext = (const float*)d_in[0];
    const float* faud  = (const float*)d_in[1];
    const int*   adj   = (const int*)d_in[2];
    const int*   smask = (const int*)d_in[3];
    const float* U1    = (const float*)d_in[6];
    const float* U2    = (const float*)d_in[7];
    const float* Pw    = (const float*)d_in[8];
    const float* Pb    = (const float*)d_in[9];
    const float* V1    = (const float*)d_in[10];
    const float* V2    = (const float*)d_in[11];
    const float* fc1w  = (const float*)d_in[12];
    const float* fc1b  = (const float*)d_in[13];
    const float* gatw  = (const float*)d_in[14];
    const float* gatb  = (const float*)d_in[15];
    const float* Wr0   = (const float*)d_in[16];
    const float* Wr1   = (const float*)d_in[17];
    const float* cwi   = (const float*)d_in[18];
    const float* cwh   = (const float*)d_in[19];
    const float* cbi   = (const float*)d_in[20];
    const float* cbh   = (const float*)d_in[21];
    const float* pwi   = (const float*)d_in[22];
    const float* pwh   = (const float*)d_in[23];
    const float* pbi   = (const float*)d_in[24];
    const float* pbh   = (const float*)d_in[25];
    const float* w0    = (const float*)d_in[26];
    const float* b0    = (const float*)d_in[27];
    const float* w1    = (const float*)d_in[28];
    const float* b1    = (const float*)d_in[29];
    const float* w2    = (const float*)d_in[30];
    const float* b2    = (const float*)d_in[31];
    float* out = (float*)d_out;
    float* ws = (float*)d_ws;

    // workspace layout (f32 words)
    float* Hcat  = ws;                        // 2,129,920
    float* gPre  = ws + 2129920;              // 2,949,120 (front: T1|T2; back: h2)
    float* T1b   = gPre;                      // 1,310,720
    float* T2b   = gPre + 1310720;            // 1,310,720
    float* CBuf  = ws + 5079040;              // 655,360 (later h1)
    uint*  WgPk  = (uint*)(ws + 5734400);     // 884,736 u32
    uint*  WrPk  = (uint*)(ws + 6619136);     // 294,912 u32
    float* gb_   = ws + 6914048;              // 4,608
    float* qpreB = ws + 6918656;              // 2,560
    u64*   X1l0  = (u64*)(ws + 6921216);      // 16,384 u64
    u64*   X2l0  = X1l0 + 16384;              //  8,192 u64
    u64*   X1l1  = X2l0 + 8192;               // 16,384 u64
    u64*   X2l1  = X1l1 + 16384;              //  8,192 u64
    unsigned short* wB = (unsigned short*)(ws + 7019520);  // 4,587,520 u16

    auto g = [&](const float* A, int lda, size_t woff, int ldw,
                 const float* bias, float* C, int ldc, int K, int N,
                 int act, int accum) {
        dim3 grid(N / 64, 1280 / 64);
        gemm_mfma<<<grid, 256, 0, stream>>>(A, lda, wB + woff, ldw, bias, C, ldc,
                                            K, act, accum);
    };

    // zero ALL exchange words each launch (kills cross-launch seq aliasing)
    hipMemsetAsync(X1l0, 0, (size_t)(16384 + 8192) * 2 * sizeof(u64), stream);

    // weight prep (independent of front-end)
    wcvt<<<17938, 256, 0, stream>>>(U1, V1, U2, V2, Pw, fc1w, cwi, pwh, w0, w1,
                                    cbi, pbh, wB, gb_);
    trans_wg3<<<3456, 256, 0, stream>>>(cwh, pwi, WgPk);
    trans_wr3<<<1152, 256, 0, stream>>>(Wr0, Wr1, WrPk);

    // Front-end fusion (bf16 MFMA)
    g(ftext, 1024, 0, 1024, nullptr, T1b, 1024, 1024, 1024, 3, 0);
    g(faud, 512, 1048576, 512, nullptr, T2b, 1024, 512, 1024, 3, 0);
    ew2<<<2560, 256, 0, stream>>>(T1b, T2b, CBuf, Hcat);
    g(CBuf, 512, 1572864, 512, Pb, Hcat + 1152, LDH, 512, 512, 0, 1);      // fused
    g(Hcat + 1152, LDH, 1835008, 512, fc1b, Hcat, LDH, 512, 384, 1, 0);    // H0

    // Two GAT/GRU layers (scan10 — proven)
    for (int l = 0; l < 2; ++l) {
        g(Hcat + l * 384, LDH, 2031616 + (size_t)l * 884736, 384,
          gb_ + l * 2304, gPre, 2304, 384, 2304, 0, 0);
        qpre_k<<<320, 256, 0, stream>>>(Hcat, l * 384, gatw + l * 768, qpreB + l * 1280);
        scan10<<<256, 512, 110592, stream>>>(Hcat, l * 384, (l + 1) * 384, gPre,
                                             WrPk + l * 147456, WgPk + l * 442368,
                                             qpreB + l * 1280, gatw + l * 768, gatb + l,
                                             adj, smask, cbh + l * 1152, pbi + l * 1152,
                                             l ? X1l1 : X1l0, l ? X2l1 : X2l0);
    }

    // Back-end MLP + log_softmax (bf16 MFMA)
    g(Hcat, LDH, 3801088, 1664, b0, CBuf, 384, 1664, 384, 1, 0);   // h1
    g(CBuf, 384, 4440064, 384, b1, gPre, 384, 384, 384, 1, 0);     // h2
    mlp_final<<<320, 256, 0, stream>>>(gPre, w2, b2, out);
}